// Round 11
// baseline (181.271 us; speedup 1.0000x reference)
//
#include <hip/hip_runtime.h>
#include <stdint.h>

typedef unsigned int u32;
typedef int v4i  __attribute__((ext_vector_type(4)));
typedef int v16i __attribute__((ext_vector_type(16)));

#define HW      3136     // 56*56
#define PADW    58
#define PADHW   3364     // 58*58

// d_ws layout
#define WA_OFF   0         // 147456 B: weight A-frags [og(4)][tap(9)][kq(4)][lane(64)][16B]
#define AI8_OFF  147456    // 32*3364*128 i8 padded activations [b][ph][pw][c]

// prep grid split
#define NB_W     128       // weight synthesis (one block per o)
#define NB_A     1792      // activation i8 transpose: 32 b * 56 h
#define NB_R     228       // ring zero: 32 b * 228 px * 8 uint4 / 256

// ---------------------------------------------------------------------------
// Prep kernel, 3 block classes.
// [0,128):      weight synthesis: sign(w)=sign(m+rv.z) (rsqrt factor > 0),
//               written as i8 +-1 directly in MFMA A-fragment lane order:
//               frag(tap,kq): byte j of lane L = sign(w[o][c][tap]),
//               o = og*32+(L&31), c = kq*32+(L>>5)*16+j.
// [128,1920):   activation sign -> i8 +-1, transposed [b][c][h][w] ->
//               [b][h+1][w+1][c] via LDS (coalesced read AND write).
// [1920,2148):  zero the padded ring (rows 0,57; cols 0,57) -> pad taps
//               contribute exactly 0 to the i8 GEMM.
__global__ __launch_bounds__(256) void k_prep(
    const float* __restrict__ x, const float* __restrict__ M,
    const float* __restrict__ Z, const float* __restrict__ rv,
    char* __restrict__ ws)
{
  int t = threadIdx.x;
  if (blockIdx.x < NB_W) {
    // ---- weight synthesis for o = blockIdx.x ----
    __shared__ float sw[1152];          // [c][tap] for this o
    int o = blockIdx.x;
    float r0 = rv[0], r1 = rv[1], r2 = rv[2], r3 = rv[3], r4 = rv[4];
    const float4* M4 = (const float4*)M;
    const float4* Z4 = (const float4*)Z;
    float4* sw4 = (float4*)sw;

    for (int j = t; j < 288; j += 256) {
      float4 a = M4[o * 288 + j];
      float4 z;
      z = Z4[0 * 36864 + o * 288 + j];
      a.x = fmaf(r0, z.x, a.x); a.y = fmaf(r0, z.y, a.y);
      a.z = fmaf(r0, z.z, a.z); a.w = fmaf(r0, z.w, a.w);
      z = Z4[1 * 36864 + o * 288 + j];
      a.x = fmaf(r1, z.x, a.x); a.y = fmaf(r1, z.y, a.y);
      a.z = fmaf(r1, z.z, a.z); a.w = fmaf(r1, z.w, a.w);
      z = Z4[2 * 36864 + o * 288 + j];
      a.x = fmaf(r2, z.x, a.x); a.y = fmaf(r2, z.y, a.y);
      a.z = fmaf(r2, z.z, a.z); a.w = fmaf(r2, z.w, a.w);
      z = Z4[3 * 36864 + o * 288 + j];
      a.x = fmaf(r3, z.x, a.x); a.y = fmaf(r3, z.y, a.y);
      a.z = fmaf(r3, z.z, a.z); a.w = fmaf(r3, z.w, a.w);
      z = Z4[4 * 36864 + o * 288 + j];
      a.x = fmaf(r4, z.x, a.x); a.y = fmaf(r4, z.y, a.y);
      a.z = fmaf(r4, z.z, a.z); a.w = fmaf(r4, z.w, a.w);
      sw4[j] = a;
    }
    __syncthreads();

    if (t < 72) {                       // t = tap*8 + kq*2 + khalf
      int tap   = t >> 3;
      int kq    = (t & 7) >> 1;
      int khalf = t & 1;
      union { char c[16]; uint4 v; } u;
#pragma unroll
      for (int j = 0; j < 16; ++j) {
        int c = kq * 32 + khalf * 16 + j;
        u.c[j] = (sw[c * 9 + tap] > 0.0f) ? (char)1 : (char)-1;
      }
      int og   = o >> 5;
      int lane = (o & 31) + 32 * khalf;
      uint4* wa = (uint4*)(ws + WA_OFF);
      wa[((og * 9 + tap) * 4 + kq) * 64 + lane] = u.v;
    }
  } else if (blockIdx.x < NB_W + NB_A) {
    // ---- activation i8 transpose for (b, h) ----
    __shared__ float sA[56 * 128];      // [w][c]
    int bidx = blockIdx.x - NB_W;
    int b = bidx / 56;
    int h = bidx - b * 56;
    int c    = t >> 1;
    int half = t & 1;
    const float4* xp = (const float4*)(x + ((size_t)(b * 128 + c) * HW + h * 56 + half * 28));
#pragma unroll
    for (int j = 0; j < 7; ++j) {
      float4 f = xp[j];
      int w = half * 28 + j * 4;
      sA[(w + 0) * 128 + c] = f.x;
      sA[(w + 1) * 128 + c] = f.y;
      sA[(w + 2) * 128 + c] = f.z;
      sA[(w + 3) * 128 + c] = f.w;
    }
    __syncthreads();
    // 448 uint4 out: i = w*8 + cchunk
    uint4* dst = (uint4*)(ws + AI8_OFF + (((size_t)b * PADW + (h + 1)) * PADW + 1) * 128);
    for (int i = t; i < 448; i += 256) {
      int w  = i >> 3;
      int cc = i & 7;
      union { char c[16]; uint4 v; } u;
#pragma unroll
      for (int j = 0; j < 16; ++j)
        u.c[j] = (sA[w * 128 + cc * 16 + j] > 0.0f) ? (char)1 : (char)-1;
      dst[i] = u.v;
    }
  } else {
    // ---- ring zero ----
    int e = (blockIdx.x - NB_W - NB_A) * 256 + t;   // < 58368
    int wd  = e & 7;
    int pxr = (e >> 3) % 228;
    int b   = (e >> 3) / 228;
    int pp;
    if      (pxr < 58)  pp = pxr;
    else if (pxr < 116) pp = 57 * PADW + (pxr - 58);
    else {
      int s = pxr - 116;
      pp = (1 + (s >> 1)) * PADW + ((s & 1) ? 57 : 0);
    }
    uint4* dst = (uint4*)(ws + AI8_OFF);
    dst[((size_t)b * PADHW + pp) * 8 + wd] = make_uint4(0, 0, 0, 0);
  }
}

// ---------------------------------------------------------------------------
// Conv as implicit GEMM on the i8 matrix cores.
// D[px, o] = sum_{tap, c} act_i8[px + off(tap)][c] * w_i8[o][c][tap]
// mfma_i32_32x32x32_i8: A = weights (m = o, 32 per og), B = activations
// (n = px, 32 consecutive), K = 32 channels -> 9 taps * 4 kq = 36 MFMA
// per 32px x 32o tile. Padding is exact (zero i8 ring contributes 0).
// A-frags (144 VGPR) loaded once per wave; each wave does 4 px-tiles.
// Block = 256 thr = 4 waves covering 16 px-tiles; grid (196, 4 og).
// Epilogue: out = (float)acc * Alpha[o], exact vs reference.
// C/D layout (guide, m74/m101): col(n=px) = lane&31,
// row(m=o_local) = (reg&3) + 8*(reg>>2) + 4*(lane>>5).
__global__ __launch_bounds__(256, 1) void k_conv(
    const char* __restrict__ ws, const float* __restrict__ Alpha,
    float* __restrict__ out)
{
  int tid   = threadIdx.x;
  int lane  = tid & 63;
  int wv    = tid >> 6;              // wave in block: 0..3
  int og    = blockIdx.y;            // 0..3 (32 o's each)
  int khalf = lane >> 5;
  int ln    = lane & 31;

  // A-fragments: weights for this og, frag-major layout from prep
  const v4i* wa = (const v4i*)(ws + WA_OFF) + (size_t)og * 36 * 64 + lane;
  v4i A[36];
#pragma unroll
  for (int f = 0; f < 36; ++f) A[f] = wa[f * 64];

  // alpha per accumulator register
  float alphaR[16];
#pragma unroll
  for (int r = 0; r < 16; ++r)
    alphaR[r] = Alpha[og * 32 + (r & 3) + 8 * (r >> 2) + 4 * khalf];

  const char* ai8 = ws + AI8_OFF;

#pragma unroll
  for (int it = 0; it < 4; ++it) {
    int tile = (blockIdx.x * 16 + wv * 4 + it);   // 0..3135
    int pxg  = tile * 32;                          // 3136 % 32 == 0: no b-cross
    int b    = pxg / HW;
    int pxb  = pxg - b * HW;                       // tile base within image
    int px   = pxb + ln;
    int h    = px / 56;
    int w    = px - h * 56;
    const char* ap = ai8 + (((size_t)b * PADW + (h + 1)) * PADW + (w + 1)) * 128
                         + khalf * 16;

    v16i acc = {0,0,0,0,0,0,0,0,0,0,0,0,0,0,0,0};
#pragma unroll
    for (int dh = 0; dh < 3; ++dh) {
#pragma unroll
      for (int dw = 0; dw < 3; ++dw) {
        const char* tp = ap + ((dh - 1) * PADW + (dw - 1)) * 128;
        int tap = dh * 3 + dw;
#pragma unroll
        for (int kq = 0; kq < 4; ++kq) {
          v4i Bf = *(const v4i*)(tp + kq * 32);
          acc = __builtin_amdgcn_mfma_i32_32x32x32_i8(A[tap * 4 + kq], Bf, acc, 0, 0, 0);
        }
      }
    }

    float* op = out + ((size_t)b * 128 + og * 32) * HW + pxb + ln;
#pragma unroll
    for (int r = 0; r < 16; ++r) {
      int olo = (r & 3) + 8 * (r >> 2) + 4 * khalf;
      op[(size_t)olo * HW] = (float)acc[r] * alphaR[r];
    }
  }
}

// ---------------------------------------------------------------------------
extern "C" void kernel_launch(void* const* d_in, const int* in_sizes, int n_in,
                              void* d_out, int out_size, void* d_ws, size_t ws_size,
                              hipStream_t stream)
{
  const float* x     = (const float*)d_in[0];
  const float* Alpha = (const float*)d_in[1];
  const float* M     = (const float*)d_in[2];
  const float* Z     = (const float*)d_in[3];
  const float* rv    = (const float*)d_in[4];
  float* out         = (float*)d_out;
  char*  ws          = (char*)d_ws;

  k_prep<<<NB_W + NB_A + NB_R, 256, 0, stream>>>(x, M, Z, rv, ws);
  k_conv<<<dim3(196, 4), 256, 0, stream>>>(ws, Alpha, out);
}